// Round 3
// baseline (211.524 us; speedup 1.0000x reference)
//
#include <hip/hip_runtime.h>
#include <hip/hip_fp16.h>

#define RES 2048
#define GROUPS 2
#define GPTS 4
#define PTS (GROUPS * GPTS)   // 8 points per thread
#define BLK 256               // 2048 blocks at N=4.19M

// 16-byte per-cell record: bytes 0-11 = int8 {c00.rgb, c01.rgb, c10.rgb, c11.rgb},
// bytes 12-13 = fp16 scale, 14-15 pad. Table 2048x2048 records = 67.1 MB in d_ws.
#define TBL_BYTES ((size_t)RES * RES * 16)

__device__ __forceinline__ float b2f(const uint4& r, int j) {
    // j is compile-time constant after unrolling -> static v_bfe_i32
    unsigned w = (j < 4) ? r.x : (j < 8) ? r.y : r.z;
    int pos = j & 3;
    return (float)((int)(w << ((3 - pos) * 8)) >> 24);
}

// Quantize one cell from two LDS row windows. Bit-identical math + packing
// order to the verified v1 pack kernel.
__device__ __forceinline__ uint4 quant12(const float* __restrict__ r0,
                                         const float* __restrict__ r1) {
    float v[12];
    #pragma unroll
    for (int j = 0; j < 6; ++j) v[j] = r0[j];       // c00.rgb, c01.rgb
    #pragma unroll
    for (int j = 0; j < 6; ++j) v[6 + j] = r1[j];   // c10.rgb, c11.rgb

    float s = 0.0f;
    #pragma unroll
    for (int j = 0; j < 12; ++j) s = fmaxf(s, fabsf(v[j]));

    __half hs = __float2half_rn(s * (1.0f / 127.0f));
    float qs = __half2float(hs);
    float inv = (qs > 0.0f) ? (1.0f / qs) : 0.0f;

    unsigned b[12];
    #pragma unroll
    for (int j = 0; j < 12; ++j) {
        int q = (int)rintf(v[j] * inv);
        q = max(-127, min(127, q));
        b[j] = (unsigned)(q & 255);
    }

    uint4 rec;
    rec.x = b[0] | (b[1] << 8) | (b[2]  << 16) | (b[3]  << 24);
    rec.y = b[4] | (b[5] << 8) | (b[6]  << 16) | (b[7]  << 24);
    rec.z = b[8] | (b[9] << 8) | (b[10] << 16) | (b[11] << 24);
    rec.w = (unsigned)__half_as_ushort(hs);
    return rec;
}

// ---------------- Pack v3: 16x128-cell strips, streaming-shaped ----------------
// Same verified memory pattern as v1 (contiguous float4 row-segments -> LDS,
// coalesced uint4 writes, identical quantization), but re-scheduled:
//   - 2048 blocks (vs 16384), 16 rows x 128 cells per block
//   - ALL 256 threads load (17 rows x 97 float4 = 1649 loads, 7 guarded
//     rounds each -> independent, vmcnt-pipelined) vs v1's 221/256 single load
//   - 8 cells/thread after one barrier; writes coalesced (64 lanes = 1KB runs)
// LDS 26.7 KB -> 5 blocks/CU = 20 waves/CU. Data budget 54 MB read + 67 MB
// write => ~20-25 us at streaming BW.
__global__ __launch_bounds__(256) void pack_kernel3(
        const float* __restrict__ fp,
        uint4* __restrict__ tbl) {
    __shared__ float lds[17][392];          // 97 float4 = 388 floats, +4 pad
    int tx = blockIdx.x;                    // 0..15   (128-cell strip in x)
    int ty = blockIdx.y;                    // 0..127  (16 cell-rows in y)
    int t  = threadIdx.x;

    const float4* fp4 = (const float4*)fp;  // 1536 float4 per grid row

    // Window: floats [384*tx .. 384*tx+386] of rows ty*16 .. ty*16+16.
    // 384*tx/4 = 96*tx -> float4-aligned. 97 float4 per row.
    #pragma unroll
    for (int it = 0; it < 7; ++it) {
        int l = t + it * 256;
        if (l < 17 * 97) {
            int r = l / 97, c = l % 97;
            int gy  = min(ty * 16 + r, RES - 1);   // r=16 @ ty=127: feeds row-2047 records, never read (yl<=2046)
            int gx4 = min(96 * tx + c, 1535);      // c=96 @ tx=15: feeds x-2047 record, never read (xl<=2046)
            float4 v = fp4[(size_t)gy * 1536 + gx4];
            lds[r][c * 4 + 0] = v.x; lds[r][c * 4 + 1] = v.y;
            lds[r][c * 4 + 2] = v.z; lds[r][c * 4 + 3] = v.w;
        }
    }
    __syncthreads();

    // 2048 cells/block, 8 per thread. ci = i*256+t -> cyl=ci>>7, cxl=ci&127:
    // per-wave writes are 64 consecutive uint4 (1KB contiguous runs).
    #pragma unroll
    for (int i = 0; i < 8; ++i) {
        int ci  = i * 256 + t;
        int cyl = ci >> 7, cxl = ci & 127;
        // cell (global x = tx*128+cxl) needs local floats cxl*3 .. cxl*3+5
        uint4 rec = quant12(&lds[cyl][cxl * 3], &lds[cyl + 1][cxl * 3]);
        int gy = ty * 16 + cyl, gx = tx * 128 + cxl;
        tbl[((size_t)gy << 11) | (unsigned)gx] = rec;
    }
}

// ---- Gather: 8 pts/thread, group-interleaved, barrier'd LDS-transposed stores ----
// UNCHANGED: counters show one 64B random line fetch per point (265 MB total),
// which is structurally minimal; ~3.5 TB/s random-access service rate is the
// fabric ceiling for this pattern (VALUBusy 5%, queues saturated at 32 waves/CU
// x 8 in-flight gathers).
__global__ __launch_bounds__(BLK) void fg2d_q8_kernel(
        const float* __restrict__ inp,
        const uint4* __restrict__ tbl,
        float* __restrict__ out,
        int n_points) {
    __shared__ float4 st[BLK * 3];          // 12 KB: one group's output per block
    int t = threadIdx.x;
    long long bb = (long long)blockIdx.x * (BLK * PTS);   // block's base point (2048/block)

    const float4* in4 = (const float4*)inp;

    if (bb + BLK * PTS <= n_points) {       // block-uniform -> barriers safe
        // ---- fast path ----
        // issue all 4 input float4 loads first (coalesced pairs)
        float4 pa[GROUPS], pb[GROUPS];
        #pragma unroll
        for (int c = 0; c < GROUPS; ++c) {
            long long pg = bb + c * (BLK * GPTS) + (long long)t * GPTS;
            long long i0 = pg >> 1;
            pa[c] = in4[i0];
            pb[c] = in4[i0 + 1];
        }

        float txs[PTS], tys[PTS];
        unsigned idx[PTS];
        #pragma unroll
        for (int c = 0; c < GROUPS; ++c) {
            float px[GPTS] = {pa[c].x, pa[c].z, pb[c].x, pb[c].z};
            float py[GPTS] = {pa[c].y, pa[c].w, pb[c].y, pb[c].w};
            #pragma unroll
            for (int j = 0; j < GPTS; ++j) {
                int k = c * GPTS + j;
                float sx = px[j] * (float)(RES - 1);
                float sy = py[j] * (float)(RES - 1);
                int xl = min(max((int)floorf(sx), 0), RES - 2);
                int yl = min(max((int)floorf(sy), 0), RES - 2);
                txs[k] = sx - (float)xl;
                tys[k] = sy - (float)yl;
                idx[k] = ((unsigned)yl << 11) | (unsigned)xl;
            }
        }

        // issue all 8 independent 16B gathers before any use
        uint4 r[PTS];
        #pragma unroll
        for (int k = 0; k < PTS; ++k) r[k] = tbl[idx[k]];

        #pragma unroll
        for (int c = 0; c < GROUPS; ++c) {
            float res[12];
            #pragma unroll
            for (int j = 0; j < GPTS; ++j) {
                int k = c * GPTS + j;
                float tx = txs[k], ty = tys[k];
                float sc = __half2float(__ushort_as_half((unsigned short)(r[k].w & 0xffffu)));
                float w00 = (1.0f - tx) * (1.0f - ty) * sc;
                float w01 = tx * (1.0f - ty) * sc;
                float w10 = (1.0f - tx) * ty * sc;
                float w11 = tx * ty * sc;
                #pragma unroll
                for (int ch = 0; ch < 3; ++ch) {
                    res[j * 3 + ch] = b2f(r[k], ch)     * w00
                                    + b2f(r[k], 3 + ch) * w01
                                    + b2f(r[k], 6 + ch) * w10
                                    + b2f(r[k], 9 + ch) * w11;
                }
            }
            // LDS transpose with explicit barriers (R5 failed without them):
            // write own 3 float4, barrier, then 3 block-contiguous stores
            // (every 64B sector fully covered -> no write amplification).
            if (c > 0) __syncthreads();     // protect st[] reuse across groups
            st[3 * t + 0] = make_float4(res[0], res[1], res[2],  res[3]);
            st[3 * t + 1] = make_float4(res[4], res[5], res[6],  res[7]);
            st[3 * t + 2] = make_float4(res[8], res[9], res[10], res[11]);
            __syncthreads();

            long long gbase = bb + c * (BLK * GPTS);
            float4* o4 = (float4*)out + ((gbase * 3) >> 2);
            o4[t]           = st[t];
            o4[BLK + t]     = st[BLK + t];
            o4[2 * BLK + t] = st[2 * BLK + t];
        }
    } else {
        // ---- guarded tail path (not taken for N=4194304) ----
        for (int c = 0; c < GROUPS; ++c) {
            long long pg = bb + c * (BLK * GPTS) + (long long)t * GPTS;
            for (int j = 0; j < GPTS; ++j) {
                long long p = pg + j;
                if (p >= n_points) continue;
                float px = inp[p * 2], py = inp[p * 2 + 1];
                float sx = px * (float)(RES - 1);
                float sy = py * (float)(RES - 1);
                int xl = min(max((int)floorf(sx), 0), RES - 2);
                int yl = min(max((int)floorf(sy), 0), RES - 2);
                float tx = sx - (float)xl, ty = sy - (float)yl;
                uint4 r = tbl[((unsigned)yl << 11) | (unsigned)xl];
                float sc = __half2float(__ushort_as_half((unsigned short)(r.w & 0xffffu)));
                float w00 = (1.0f - tx) * (1.0f - ty) * sc;
                float w01 = tx * (1.0f - ty) * sc;
                float w10 = (1.0f - tx) * ty * sc;
                float w11 = tx * ty * sc;
                for (int ch = 0; ch < 3; ++ch) {
                    out[p * 3 + ch] = b2f(r, ch) * w00 + b2f(r, 3 + ch) * w01
                                    + b2f(r, 6 + ch) * w10 + b2f(r, 9 + ch) * w11;
                }
            }
        }
    }
}

// ---------------- Fallback: direct fp32 gather (R1) ----------------
__global__ __launch_bounds__(256) void fg2d_kernel(
        const float* __restrict__ inp,
        const float* __restrict__ fp,
        float* __restrict__ out,
        int n_points) {
    int tid = blockIdx.x * blockDim.x + threadIdx.x;
    int p0 = tid * 4;
    if (p0 >= n_points) return;

    const float4* in4 = (const float4*)inp;
    float4 a = in4[tid * 2 + 0];
    float4 b = in4[tid * 2 + 1];

    float px[4] = {a.x, a.z, b.x, b.z};
    float py[4] = {a.y, a.w, b.y, b.w};

    const float* rowlo[4];
    const float* rowhi[4];
    float txs[4], tys[4];

    #pragma unroll
    for (int k = 0; k < 4; ++k) {
        float sx = px[k] * (float)(RES - 1);
        float sy = py[k] * (float)(RES - 1);
        int xl = min(max((int)floorf(sx), 0), RES - 2);
        int yl = min(max((int)floorf(sy), 0), RES - 2);
        txs[k] = sx - (float)xl;
        tys[k] = sy - (float)yl;
        rowlo[k] = fp + ((size_t)yl * RES + xl) * 3;
        rowhi[k] = rowlo[k] + (size_t)RES * 3;
    }

    float c0v[4][6], c1v[4][6];
    #pragma unroll
    for (int k = 0; k < 4; ++k) {
        #pragma unroll
        for (int j = 0; j < 6; ++j) c0v[k][j] = rowlo[k][j];
        #pragma unroll
        for (int j = 0; j < 6; ++j) c1v[k][j] = rowhi[k][j];
    }

    float res[12];
    #pragma unroll
    for (int k = 0; k < 4; ++k) {
        float tx = txs[k], ty = tys[k];
        #pragma unroll
        for (int ch = 0; ch < 3; ++ch) {
            float top = c0v[k][ch] * (1.0f - tx) + c0v[k][3 + ch] * tx;
            float bot = c1v[k][ch] * (1.0f - tx) + c1v[k][3 + ch] * tx;
            res[k * 3 + ch] = top * (1.0f - ty) + bot * ty;
        }
    }

    float4* out4 = (float4*)(out + (size_t)p0 * 3);
    out4[0] = make_float4(res[0], res[1], res[2], res[3]);
    out4[1] = make_float4(res[4], res[5], res[6], res[7]);
    out4[2] = make_float4(res[8], res[9], res[10], res[11]);
}

extern "C" void kernel_launch(void* const* d_in, const int* in_sizes, int n_in,
                              void* d_out, int out_size, void* d_ws, size_t ws_size,
                              hipStream_t stream) {
    const float* inp = (const float*)d_in[0];   // (N, 2) fp32
    const float* fp  = (const float*)d_in[1];   // (2048, 2048, 3) fp32
    float* out = (float*)d_out;                 // (N, 3) fp32

    int n_points = in_sizes[0] / 2;

    if (ws_size >= TBL_BYTES) {
        uint4* tbl = (uint4*)d_ws;
        dim3 pack_grid(RES / 128, RES / 16);    // 16 x 128 = 2048 blocks
        pack_kernel3<<<pack_grid, 256, 0, stream>>>(fp, tbl);

        int n_blocks = (n_points + BLK * PTS - 1) / (BLK * PTS);
        fg2d_q8_kernel<<<n_blocks, BLK, 0, stream>>>(inp, tbl, out, n_points);
    } else {
        int n_threads = (n_points + 3) / 4;
        int grid = (n_threads + 255) / 256;
        fg2d_kernel<<<grid, 256, 0, stream>>>(inp, fp, out, n_points);
    }
}

// Round 4
// 207.865 us; speedup vs baseline: 1.0176x; 1.0176x over previous
//
#include <hip/hip_runtime.h>
#include <hip/hip_fp16.h>

#define RES 2048
#define GROUPS 2
#define GPTS 4
#define PTS (GROUPS * GPTS)   // 8 points per thread
#define BLK 256               // 2048 blocks at N=4.19M

// 16-byte per-cell record: bytes 0-11 = int8 {c00.rgb, c01.rgb, c10.rgb, c11.rgb},
// bytes 12-13 = fp16 scale, 14-15 pad. Table 2048x2048 records = 67.1 MB in d_ws.
#define TBL_BYTES ((size_t)RES * RES * 16)

__device__ __forceinline__ float b2f(const uint4& r, int j) {
    // j is compile-time constant after unrolling -> static v_bfe_i32
    unsigned w = (j < 4) ? r.x : (j < 8) ? r.y : r.z;
    int pos = j & 3;
    return (float)((int)(w << ((3 - pos) * 8)) >> 24);
}

// ---------------- Tiled pack: 16x16 cells per block, LDS-staged ----------------
// FINAL: the dual-verified v1 pack (207.5 / 208.4 us totals). Budget analysis
// (R1/R3 differentials): pack ~25 us in both this shape and the streaming v3
// shape -> at its ~20 us data-budget floor; not worth further risk.
__global__ __launch_bounds__(256) void pack_kernel(
        const float* __restrict__ fp,
        uint4* __restrict__ tbl) {
    __shared__ float lds[17][52];
    int tx = blockIdx.x;            // 0..127
    int ty = blockIdx.y;            // 0..127
    int t  = threadIdx.x;

    const float4* fp4 = (const float4*)fp;   // 1536 float4 per grid row
    if (t < 17 * 13) {
        int r = t / 13, j = t % 13;
        int gy  = min(ty * 16 + r, RES - 1);     // clamped dups only feed unused records
        int gx4 = min(tx * 12 + j, 1535);
        float4 v = fp4[(size_t)gy * 1536 + gx4];
        lds[r][j * 4 + 0] = v.x; lds[r][j * 4 + 1] = v.y;
        lds[r][j * 4 + 2] = v.z; lds[r][j * 4 + 3] = v.w;
    }
    __syncthreads();

    int cyl = t >> 4, cxl = t & 15;
    const float* r0 = &lds[cyl][cxl * 3];
    const float* r1 = &lds[cyl + 1][cxl * 3];

    float v[12];
    #pragma unroll
    for (int j = 0; j < 6; ++j) v[j] = r0[j];       // c00.rgb, c01.rgb
    #pragma unroll
    for (int j = 0; j < 6; ++j) v[6 + j] = r1[j];   // c10.rgb, c11.rgb

    float s = 0.0f;
    #pragma unroll
    for (int j = 0; j < 12; ++j) s = fmaxf(s, fabsf(v[j]));

    __half hs = __float2half_rn(s * (1.0f / 127.0f));
    float qs = __half2float(hs);
    float inv = (qs > 0.0f) ? (1.0f / qs) : 0.0f;

    unsigned b[12];
    #pragma unroll
    for (int j = 0; j < 12; ++j) {
        int q = (int)rintf(v[j] * inv);
        q = max(-127, min(127, q));
        b[j] = (unsigned)(q & 255);
    }

    uint4 rec;
    rec.x = b[0] | (b[1] << 8) | (b[2]  << 16) | (b[3]  << 24);
    rec.y = b[4] | (b[5] << 8) | (b[6]  << 16) | (b[7]  << 24);
    rec.z = b[8] | (b[9] << 8) | (b[10] << 16) | (b[11] << 24);
    rec.w = (unsigned)__half_as_ushort(hs);

    int gy = ty * 16 + cyl, gx = tx * 16 + cxl;
    tbl[((size_t)gy << 11) | gx] = rec;
}

// ---- Gather: 8 pts/thread, group-interleaved, barrier'd LDS-transposed stores ----
// UNCHANGED (pinned across 4 rounds): FETCH = 265 MB = 4.19M x 64B random line
// fetches + 33.5 MB input stream -> one fabric transaction per point, the
// structural minimum (any sort/permute scheme pays the same randomness on the
// write side). ~3.5 TB/s random-64B service rate with VALUBusy 5% and 16K
// outstanding requests/CU = memory-system ceiling for this pattern.
__global__ __launch_bounds__(BLK) void fg2d_q8_kernel(
        const float* __restrict__ inp,
        const uint4* __restrict__ tbl,
        float* __restrict__ out,
        int n_points) {
    __shared__ float4 st[BLK * 3];          // 12 KB: one group's output per block
    int t = threadIdx.x;
    long long bb = (long long)blockIdx.x * (BLK * PTS);   // block's base point (2048/block)

    const float4* in4 = (const float4*)inp;

    if (bb + BLK * PTS <= n_points) {       // block-uniform -> barriers safe
        // ---- fast path ----
        // issue all 4 input float4 loads first (coalesced pairs)
        float4 pa[GROUPS], pb[GROUPS];
        #pragma unroll
        for (int c = 0; c < GROUPS; ++c) {
            long long pg = bb + c * (BLK * GPTS) + (long long)t * GPTS;
            long long i0 = pg >> 1;
            pa[c] = in4[i0];
            pb[c] = in4[i0 + 1];
        }

        float txs[PTS], tys[PTS];
        unsigned idx[PTS];
        #pragma unroll
        for (int c = 0; c < GROUPS; ++c) {
            float px[GPTS] = {pa[c].x, pa[c].z, pb[c].x, pb[c].z};
            float py[GPTS] = {pa[c].y, pa[c].w, pb[c].y, pb[c].w};
            #pragma unroll
            for (int j = 0; j < GPTS; ++j) {
                int k = c * GPTS + j;
                float sx = px[j] * (float)(RES - 1);
                float sy = py[j] * (float)(RES - 1);
                int xl = min(max((int)floorf(sx), 0), RES - 2);
                int yl = min(max((int)floorf(sy), 0), RES - 2);
                txs[k] = sx - (float)xl;
                tys[k] = sy - (float)yl;
                idx[k] = ((unsigned)yl << 11) | (unsigned)xl;
            }
        }

        // issue all 8 independent 16B gathers before any use
        uint4 r[PTS];
        #pragma unroll
        for (int k = 0; k < PTS; ++k) r[k] = tbl[idx[k]];

        #pragma unroll
        for (int c = 0; c < GROUPS; ++c) {
            float res[12];
            #pragma unroll
            for (int j = 0; j < GPTS; ++j) {
                int k = c * GPTS + j;
                float tx = txs[k], ty = tys[k];
                float sc = __half2float(__ushort_as_half((unsigned short)(r[k].w & 0xffffu)));
                float w00 = (1.0f - tx) * (1.0f - ty) * sc;
                float w01 = tx * (1.0f - ty) * sc;
                float w10 = (1.0f - tx) * ty * sc;
                float w11 = tx * ty * sc;
                #pragma unroll
                for (int ch = 0; ch < 3; ++ch) {
                    res[j * 3 + ch] = b2f(r[k], ch)     * w00
                                    + b2f(r[k], 3 + ch) * w01
                                    + b2f(r[k], 6 + ch) * w10
                                    + b2f(r[k], 9 + ch) * w11;
                }
            }
            // LDS transpose with explicit barriers (R5 failed without them):
            // write own 3 float4, barrier, then 3 block-contiguous stores
            // (every 64B sector fully covered -> no write amplification).
            if (c > 0) __syncthreads();     // protect st[] reuse across groups
            st[3 * t + 0] = make_float4(res[0], res[1], res[2],  res[3]);
            st[3 * t + 1] = make_float4(res[4], res[5], res[6],  res[7]);
            st[3 * t + 2] = make_float4(res[8], res[9], res[10], res[11]);
            __syncthreads();

            long long gbase = bb + c * (BLK * GPTS);
            float4* o4 = (float4*)out + ((gbase * 3) >> 2);
            o4[t]           = st[t];
            o4[BLK + t]     = st[BLK + t];
            o4[2 * BLK + t] = st[2 * BLK + t];
        }
    } else {
        // ---- guarded tail path (not taken for N=4194304) ----
        for (int c = 0; c < GROUPS; ++c) {
            long long pg = bb + c * (BLK * GPTS) + (long long)t * GPTS;
            for (int j = 0; j < GPTS; ++j) {
                long long p = pg + j;
                if (p >= n_points) continue;
                float px = inp[p * 2], py = inp[p * 2 + 1];
                float sx = px * (float)(RES - 1);
                float sy = py * (float)(RES - 1);
                int xl = min(max((int)floorf(sx), 0), RES - 2);
                int yl = min(max((int)floorf(sy), 0), RES - 2);
                float tx = sx - (float)xl, ty = sy - (float)yl;
                uint4 r = tbl[((unsigned)yl << 11) | (unsigned)xl];
                float sc = __half2float(__ushort_as_half((unsigned short)(r.w & 0xffffu)));
                float w00 = (1.0f - tx) * (1.0f - ty) * sc;
                float w01 = tx * (1.0f - ty) * sc;
                float w10 = (1.0f - tx) * ty * sc;
                float w11 = tx * ty * sc;
                for (int ch = 0; ch < 3; ++ch) {
                    out[p * 3 + ch] = b2f(r, ch) * w00 + b2f(r, 3 + ch) * w01
                                    + b2f(r, 6 + ch) * w10 + b2f(r, 9 + ch) * w11;
                }
            }
        }
    }
}

// ---------------- Fallback: direct fp32 gather (R1) ----------------
__global__ __launch_bounds__(256) void fg2d_kernel(
        const float* __restrict__ inp,
        const float* __restrict__ fp,
        float* __restrict__ out,
        int n_points) {
    int tid = blockIdx.x * blockDim.x + threadIdx.x;
    int p0 = tid * 4;
    if (p0 >= n_points) return;

    const float4* in4 = (const float4*)inp;
    float4 a = in4[tid * 2 + 0];
    float4 b = in4[tid * 2 + 1];

    float px[4] = {a.x, a.z, b.x, b.z};
    float py[4] = {a.y, a.w, b.y, b.w};

    const float* rowlo[4];
    const float* rowhi[4];
    float txs[4], tys[4];

    #pragma unroll
    for (int k = 0; k < 4; ++k) {
        float sx = px[k] * (float)(RES - 1);
        float sy = py[k] * (float)(RES - 1);
        int xl = min(max((int)floorf(sx), 0), RES - 2);
        int yl = min(max((int)floorf(sy), 0), RES - 2);
        txs[k] = sx - (float)xl;
        tys[k] = sy - (float)yl;
        rowlo[k] = fp + ((size_t)yl * RES + xl) * 3;
        rowhi[k] = rowlo[k] + (size_t)RES * 3;
    }

    float c0v[4][6], c1v[4][6];
    #pragma unroll
    for (int k = 0; k < 4; ++k) {
        #pragma unroll
        for (int j = 0; j < 6; ++j) c0v[k][j] = rowlo[k][j];
        #pragma unroll
        for (int j = 0; j < 6; ++j) c1v[k][j] = rowhi[k][j];
    }

    float res[12];
    #pragma unroll
    for (int k = 0; k < 4; ++k) {
        float tx = txs[k], ty = tys[k];
        #pragma unroll
        for (int ch = 0; ch < 3; ++ch) {
            float top = c0v[k][ch] * (1.0f - tx) + c0v[k][3 + ch] * tx;
            float bot = c1v[k][ch] * (1.0f - tx) + c1v[k][3 + ch] * tx;
            res[k * 3 + ch] = top * (1.0f - ty) + bot * ty;
        }
    }

    float4* out4 = (float4*)(out + (size_t)p0 * 3);
    out4[0] = make_float4(res[0], res[1], res[2], res[3]);
    out4[1] = make_float4(res[4], res[5], res[6], res[7]);
    out4[2] = make_float4(res[8], res[9], res[10], res[11]);
}

extern "C" void kernel_launch(void* const* d_in, const int* in_sizes, int n_in,
                              void* d_out, int out_size, void* d_ws, size_t ws_size,
                              hipStream_t stream) {
    const float* inp = (const float*)d_in[0];   // (N, 2) fp32
    const float* fp  = (const float*)d_in[1];   // (2048, 2048, 3) fp32
    float* out = (float*)d_out;                 // (N, 3) fp32

    int n_points = in_sizes[0] / 2;

    if (ws_size >= TBL_BYTES) {
        uint4* tbl = (uint4*)d_ws;
        dim3 pack_grid(RES / 16, RES / 16);
        pack_kernel<<<pack_grid, 256, 0, stream>>>(fp, tbl);

        int n_blocks = (n_points + BLK * PTS - 1) / (BLK * PTS);
        fg2d_q8_kernel<<<n_blocks, BLK, 0, stream>>>(inp, tbl, out, n_points);
    } else {
        int n_threads = (n_points + 3) / 4;
        int grid = (n_threads + 255) / 256;
        fg2d_kernel<<<grid, 256, 0, stream>>>(inp, fp, out, n_points);
    }
}